// Round 14
// baseline (44.080 us; speedup 1.0000x reference)
//
#include <hip/hip_runtime.h>
#include <math.h>

constexpr int In = 128, Rn = 36, Cn = 64, Ln = 32, Dn = 512;
constexpr int Mn = In * Rn;              // 4608
constexpr int Nn = Cn * Ln;              // 2048
// ws layout (float units)
constexpr size_t ABOFF = 0;                            // images bf16 linear (Mn*Dn u16)
constexpr size_t BBOFF = (size_t)Mn * Dn / 2;          // captions bf16 FRAGMENT-SHUFFLED
constexpr size_t GBOFF = BBOFF + (size_t)Nn * Dn / 2;  // Gb bf16 [In][48][64]
constexpr size_t CNOFF = GBOFF + (size_t)In * 48 * 64 / 2;
constexpr size_t WSFLOATS = CNOFF + (size_t)Cn * Ln;   // ~7.6 MB
constexpr float EPSf = 1e-8f, LLSE = 6.0f, LSM = 9.0f, SLOPE = 0.1f;

using short8 = __attribute__((ext_vector_type(8))) short;
using f32x4  = __attribute__((ext_vector_type(4))) float;

__device__ __forceinline__ float dot4(float4 a, float4 b) {
  return a.x * b.x + a.y * b.y + a.z * b.z + a.w * b.w;
}

__device__ __forceinline__ unsigned short f2bf(float x) {   // RNE
  union { float f; unsigned u; } v; v.f = x;
  unsigned r = v.u + 0x7fffu + ((v.u >> 16) & 1u);
  return (unsigned short)(r >> 16);
}

__device__ __forceinline__ short8 pack8(float4 u, float4 v) {
  short8 s;
  s[0] = (short)f2bf(u.x); s[1] = (short)f2bf(u.y); s[2] = (short)f2bf(u.z); s[3] = (short)f2bf(u.w);
  s[4] = (short)f2bf(v.x); s[5] = (short)f2bf(v.y); s[6] = (short)f2bf(v.z); s[7] = (short)f2bf(v.w);
  return s;
}

// ---------------------------------------------------------------------------
// Prepass, grid 704 (unchanged from round 12):
//  blocks 0..127   : per-image fp32->bf16 cvt (linear) + G via MFMA
//  blocks 128..639 : caption fp32->bf16 cvt into fragment-major layout
//  blocks 640..703 : caption sq-norms (fp32)
// ---------------------------------------------------------------------------
extern "C" __global__ __launch_bounds__(256, 2)
void scan_pre(const float* __restrict__ images, const float* __restrict__ captions,
              float* __restrict__ ws)
{
  __shared__ unsigned short sI[48 * 520];
  const int tid = threadIdx.x;
  const int bx = blockIdx.x;
  const short8 z8 = {0, 0, 0, 0, 0, 0, 0, 0};

  if (bx < 128) {
    const int i = bx;
    const float* gi = images + (size_t)i * Rn * Dn;
    unsigned short* Ab = (unsigned short*)(ws + ABOFF) + (size_t)i * Rn * Dn;
    for (int q = 0; q < 9; ++q) {
      int ch = tid + q * 256;
      int r = ch >> 6, c8 = (ch & 63) * 8;
      float4 u = *reinterpret_cast<const float4*>(gi + r * Dn + c8);
      float4 v = *reinterpret_cast<const float4*>(gi + r * Dn + c8 + 4);
      short8 p = pack8(u, v);
      *reinterpret_cast<short8*>(Ab + r * Dn + c8) = p;
      *reinterpret_cast<short8*>(&sI[r * 520 + c8]) = p;
    }
    for (int q = 0; q < 3; ++q) {
      int ch = tid + q * 256;
      int r = 36 + (ch >> 6), c8 = (ch & 63) * 8;
      *reinterpret_cast<short8*>(&sI[r * 520 + c8]) = z8;
    }
    __syncthreads();
    const int lane = tid & 63, wv = tid >> 6;
    const int lr = lane & 15, lk = lane >> 4;
    unsigned short* gb = (unsigned short*)(ws + GBOFF) + (size_t)i * 48 * 64;
    for (int t = wv; t < 9; t += 4) {
      const int mt = t / 3, nt = t - mt * 3;
      f32x4 acc = {0.f, 0.f, 0.f, 0.f};
      for (int k = 0; k < 16; ++k) {
        short8 af = *reinterpret_cast<const short8*>(&sI[(mt * 16 + lr) * 520 + k * 32 + lk * 8]);
        short8 bf = *reinterpret_cast<const short8*>(&sI[(nt * 16 + lr) * 520 + k * 32 + lk * 8]);
        acc = __builtin_amdgcn_mfma_f32_16x16x32_bf16(af, bf, acc, 0, 0, 0);
      }
      #pragma unroll
      for (int j = 0; j < 4; ++j)
        gb[(mt * 16 + lk * 4 + j) * 64 + nt * 16 + lr] = f2bf(acc[j]);
    }
    if (tid < 96) {
      int r = tid >> 1, h = tid & 1;
      *reinterpret_cast<short8*>(gb + r * 64 + 48 + h * 8) = z8;
    }
    return;
  }
  if (bx < 640) {
    const int chunk = (bx - 128) * 256 + tid;        // 0..131071 short8 chunks
    const int c  = chunk >> 11;
    const int cc = chunk & 2047;
    const int ln = cc & 63;
    const int fc = cc >> 6;             // (t,ks,y)
    const int t  = fc >> 2;
    const int ks = (fc >> 1) & 1;
    const int y  = fc & 1;
    const int lr = ln & 15, lk = ln >> 4;
    const float* src = captions + ((size_t)c * Ln + y * 16 + lr) * Dn
                     + t * 64 + ks * 32 + lk * 8;
    float4 u = *reinterpret_cast<const float4*>(src);
    float4 v = *reinterpret_cast<const float4*>(src + 4);
    unsigned short* dst = (unsigned short*)(ws + BBOFF) + (size_t)chunk * 8;
    *reinterpret_cast<short8*>(dst) = pack8(u, v);
    return;
  }
  {
    const int c = bx - 640;
    const float* gc = captions + (size_t)c * Ln * Dn;
    const int l = tid >> 3, p = tid & 7;
    float s = 0.f;
    #pragma unroll
    for (int t = 0; t < 16; ++t) {
      float4 v = *reinterpret_cast<const float4*>(gc + l * Dn + p * 64 + t * 4);
      s += dot4(v, v);
    }
    s += __shfl_xor(s, 1, 64); s += __shfl_xor(s, 2, 64); s += __shfl_xor(s, 4, 64);
    if (p == 0) ws[CNOFF + c * Ln + l] = s;
  }
}

// ---------------------------------------------------------------------------
// Fused (round-12 structure, proven): block = 1 image x 4 captions (256 thr,
// wave = caption). Full image staged ONCE in LDS; B fragments direct-global
// (pre-shuffled, coalesced), prefetched TWO K-steps deep. K-loop barrier-free.
// ET overlays the zeroed pad rows (exact r12 arithmetic). Grid 2048.
// ---------------------------------------------------------------------------
extern "C" __global__ __launch_bounds__(256, 3)
void scan_fused(const float* __restrict__ ws, const int* __restrict__ cap_lens,
                float* __restrict__ out)
{
  __shared__ unsigned short sA[48 * 520];      // 49,920 B
  const unsigned short* Ab = (const unsigned short*)(ws + ABOFF);
  const unsigned short* Bf = (const unsigned short*)(ws + BBOFF);
  const unsigned short* GbAll = (const unsigned short*)(ws + GBOFF);
  const float* cnArr = ws + CNOFF;

  const int tid = threadIdx.x;
  int bid = blockIdx.x;                        // 2048 blocks; 8 XCD chunks of 256
  bid = (bid & 7) * 256 + (bid >> 3);
  const int ig = bid >> 4;
  const int cg = bid & 15;
  const int lane = tid & 63, wv = tid >> 6;
  const int lr = lane & 15, lk = lane >> 4;
  const int cap = cg * 4 + wv;
  const int len = cap_lens[cap];
  const short8 z8 = {0, 0, 0, 0, 0, 0, 0, 0};

  // B fragment pointer + 2-deep prefetch issued BEFORE the staging barrier
  const unsigned short* gBp = Bf + (size_t)cap * 16384 + lane * 8;
  short8 bc[4], bn[4], b2[4];
  #pragma unroll
  for (int f = 0; f < 4; ++f)
    bc[f] = *reinterpret_cast<const short8*>(gBp + f * 512);
  #pragma unroll
  for (int f = 0; f < 4; ++f)
    bn[f] = *reinterpret_cast<const short8*>(gBp + 2048 + f * 512);

  // ---- prologue: stage full image + zero pad rows; ONE barrier ----
  {
    const unsigned short* Abi = Ab + (size_t)ig * (Rn * Dn);
    #pragma unroll
    for (int q = 0; q < 9; ++q) {
      int ch = tid + q * 256;
      int r = ch >> 6, c8 = (ch & 63) * 8;
      *reinterpret_cast<short8*>(&sA[r * 520 + c8]) =
        *reinterpret_cast<const short8*>(Abi + r * Dn + c8);
    }
    #pragma unroll
    for (int q = 0; q < 3; ++q) {
      int ch = tid + q * 256;
      int r = 36 + (ch >> 6), c8 = (ch & 63) * 8;
      *reinterpret_cast<short8*>(&sA[r * 520 + c8]) = z8;
    }
  }
  __syncthreads();

  // ---- barrier-free K-loop: B direct-global (2-deep prefetch), A from LDS --
  const unsigned short* rA = &sA[lr * 520 + lk * 8];

  f32x4 acc[3][2];
  #pragma unroll
  for (int x = 0; x < 3; ++x)
    #pragma unroll
    for (int y = 0; y < 2; ++y) acc[x][y] = {0.f, 0.f, 0.f, 0.f};

  #pragma unroll 2
  for (int t = 0; t < 8; ++t) {
    if (t < 6) {
      #pragma unroll
      for (int f = 0; f < 4; ++f)
        b2[f] = *reinterpret_cast<const short8*>(gBp + (t + 2) * 2048 + f * 512);
    }
    #pragma unroll
    for (int ks = 0; ks < 2; ++ks) {
      short8 af[3];
      #pragma unroll
      for (int x = 0; x < 3; ++x)
        af[x] = *reinterpret_cast<const short8*>(rA + x * 8320 + t * 64 + ks * 32);
      #pragma unroll
      for (int x = 0; x < 3; ++x)
        #pragma unroll
        for (int y = 0; y < 2; ++y)
          acc[x][y] = __builtin_amdgcn_mfma_f32_16x16x32_bf16(af[x], bc[ks * 2 + y], acc[x][y], 0, 0, 0);
    }
    if (t < 7) {
      #pragma unroll
      for (int f = 0; f < 4; ++f) bc[f] = bn[f];
    }
    if (t < 6) {
      #pragma unroll
      for (int f = 0; f < 4; ++f) bn[f] = b2[f];
    }
  }

  // prefetch G fragments + caption norms while VALU epilogue runs
  const unsigned short* Gb = GbAll + (size_t)ig * 48 * 64;
  short8 gfr[3][2];
  #pragma unroll
  for (int x = 0; x < 3; ++x)
    #pragma unroll
    for (int ks = 0; ks < 2; ++ks)
      gfr[x][ks] = *reinterpret_cast<const short8*>(Gb + (x * 16 + lr) * 64 + ks * 32 + lk * 8);
  const float cn0 = cnArr[cap * 32 + lr];
  const float cn1 = cnArr[cap * 32 + 16 + lr];

  // ---- epilogue (per wave = per caption) ----
  float s[3][2][4];
  #pragma unroll
  for (int x = 0; x < 3; ++x)
    #pragma unroll
    for (int y = 0; y < 2; ++y) {
      const int l = y * 16 + lr;
      #pragma unroll
      for (int j = 0; j < 4; ++j) {
        float v = acc[x][y][j];
        v = v > 0.f ? v : SLOPE * v;
        if (l >= len) v = 0.f;
        s[x][y][j] = v;
      }
    }

  float zinv[3][4];
  #pragma unroll
  for (int x = 0; x < 3; ++x)
    #pragma unroll
    for (int j = 0; j < 4; ++j) {
      float t = s[x][0][j] * s[x][0][j] + s[x][1][j] * s[x][1][j];
      t += __shfl_xor(t, 1, 64); t += __shfl_xor(t, 2, 64);
      t += __shfl_xor(t, 4, 64); t += __shfl_xor(t, 8, 64);
      zinv[x][j] = LSM / (sqrtf(t) + EPSf);
    }

  const bool x2ok = (lk == 0);
  float mcol[2] = {-1e30f, -1e30f};
  #pragma unroll
  for (int x = 0; x < 3; ++x)
    #pragma unroll
    for (int y = 0; y < 2; ++y)
      #pragma unroll
      for (int j = 0; j < 4; ++j) {
        float zz = s[x][y][j] * zinv[x][j];
        s[x][y][j] = zz;
        if (x < 2 || x2ok) mcol[y] = fmaxf(mcol[y], zz);
      }
  #pragma unroll
  for (int y = 0; y < 2; ++y) {
    mcol[y] = fmaxf(mcol[y], __shfl_xor(mcol[y], 16, 64));
    mcol[y] = fmaxf(mcol[y], __shfl_xor(mcol[y], 32, 64));
  }

  float e[3][2][4];
  float esum[2] = {0.f, 0.f}, num[2] = {0.f, 0.f};
  #pragma unroll
  for (int x = 0; x < 3; ++x)
    #pragma unroll
    for (int y = 0; y < 2; ++y)
      #pragma unroll
      for (int j = 0; j < 4; ++j) {
        float ev = (x < 2 || x2ok) ? __expf(s[x][y][j] - mcol[y]) : 0.f;
        e[x][y][j] = ev;
        esum[y] += ev;
        num[y] = fmaf(ev, acc[x][y][j], num[y]);
      }
  #pragma unroll
  for (int y = 0; y < 2; ++y) {
    esum[y] += __shfl_xor(esum[y], 16, 64); esum[y] += __shfl_xor(esum[y], 32, 64);
    num[y]  += __shfl_xor(num[y], 16, 64);  num[y]  += __shfl_xor(num[y], 32, 64);
  }

  // ---- ET overlay on the ZEROED pad rows (exact r12 arithmetic) ----
  __syncthreads();
  unsigned short* ET = &sA[36 * 520 + wv * 1552];
  #pragma unroll
  for (int x = 0; x < 3; ++x)
    #pragma unroll
    for (int y = 0; y < 2; ++y)
      #pragma unroll
      for (int j = 0; j < 4; ++j)
        ET[(y * 16 + lr) * 48 + (x * 16 + lk * 4 + j)] = f2bf(e[x][y][j]);

  f32x4 vac[3][2];
  #pragma unroll
  for (int x = 0; x < 3; ++x)
    #pragma unroll
    for (int y = 0; y < 2; ++y) vac[x][y] = {0.f, 0.f, 0.f, 0.f};
  #pragma unroll
  for (int ks = 0; ks < 2; ++ks) {
    short8 efr[2];
    #pragma unroll
    for (int y = 0; y < 2; ++y)
      efr[y] = *reinterpret_cast<const short8*>(&ET[(y * 16 + lr) * 48 + ks * 32 + lk * 8]);
    #pragma unroll
    for (int x = 0; x < 3; ++x)
      #pragma unroll
      for (int y = 0; y < 2; ++y)
        vac[x][y] = __builtin_amdgcn_mfma_f32_16x16x32_bf16(gfr[x][ks], efr[y], vac[x][y], 0, 0, 0);
  }
  float wn[2] = {0.f, 0.f};
  #pragma unroll
  for (int x = 0; x < 3; ++x)
    #pragma unroll
    for (int y = 0; y < 2; ++y)
      #pragma unroll
      for (int j = 0; j < 4; ++j)
        wn[y] = fmaf(e[x][y][j], vac[x][y][j], wn[y]);
  #pragma unroll
  for (int y = 0; y < 2; ++y) {
    wn[y] += __shfl_xor(wn[y], 16, 64); wn[y] += __shfl_xor(wn[y], 32, 64);
  }

  float sc[2];
  #pragma unroll
  for (int y = 0; y < 2; ++y) {
    const int l = y * 16 + lr;
    const float cn = y ? cn1 : cn0;
    float inv = 1.f / esum[y];
    float nm = num[y] * inv;
    float w = fmaxf(wn[y], 0.f) * inv * inv;
    float den = fmaxf(sqrtf(cn), EPSf) * fmaxf(sqrtf(w), EPSf);
    sc[y] = (l < len) ? (nm / den) * LLSE : -INFINITY;
  }
  float mx = fmaxf(sc[0], sc[1]);
  mx = fmaxf(mx, __shfl_xor(mx, 1, 64)); mx = fmaxf(mx, __shfl_xor(mx, 2, 64));
  mx = fmaxf(mx, __shfl_xor(mx, 4, 64)); mx = fmaxf(mx, __shfl_xor(mx, 8, 64));
  float ex = __expf(sc[0] - mx) + __expf(sc[1] - mx);
  ex += __shfl_xor(ex, 1, 64); ex += __shfl_xor(ex, 2, 64);
  ex += __shfl_xor(ex, 4, 64); ex += __shfl_xor(ex, 8, 64);
  if (lane == 0) out[ig * Cn + cap] = (mx + __logf(ex)) / LLSE;
}

extern "C" void kernel_launch(void* const* d_in, const int* in_sizes, int n_in,
                              void* d_out, int out_size, void* d_ws, size_t ws_size,
                              hipStream_t stream) {
  const float* images   = (const float*)d_in[0];
  const float* captions = (const float*)d_in[1];
  const int*   cap_lens = (const int*)d_in[2];
  float* out = (float*)d_out;
  float* ws  = (float*)d_ws;
  if (ws_size < WSFLOATS * sizeof(float)) return;

  hipLaunchKernelGGL(scan_pre, dim3(704), dim3(256), 0, stream,
                     images, captions, ws);
  hipLaunchKernelGGL(scan_fused, dim3(In * 16), dim3(256), 0, stream,
                     ws, cap_lens, out);
}

// Round 15
// 42.319 us; speedup vs baseline: 1.0416x; 1.0416x over previous
//
#include <hip/hip_runtime.h>
#include <math.h>

constexpr int In = 128, Rn = 36, Cn = 64, Ln = 32, Dn = 512;
constexpr int Mn = In * Rn;              // 4608
constexpr int Nn = Cn * Ln;              // 2048
// ws layout (float units)
constexpr size_t AFOFF = 0;                               // images bf16 FRAGMENT-MAJOR
constexpr size_t AFSZ  = (size_t)In * 24576 / 2;          // 8t*2ks*3x*64lane*8 shorts/img
constexpr size_t BBOFF = AFSZ;                            // captions bf16 FRAGMENT-MAJOR
constexpr size_t GBOFF = BBOFF + (size_t)Nn * Dn / 2;     // Gb bf16 [In][48][64]
constexpr size_t CNOFF = GBOFF + (size_t)In * 48 * 64 / 2;
constexpr size_t WSFLOATS = CNOFF + (size_t)Cn * Ln;      // ~9.2 MB
constexpr float EPSf = 1e-8f, LLSE = 6.0f, LSM = 9.0f, SLOPE = 0.1f;

using short8 = __attribute__((ext_vector_type(8))) short;
using f32x4  = __attribute__((ext_vector_type(4))) float;

__device__ __forceinline__ float dot4(float4 a, float4 b) {
  return a.x * b.x + a.y * b.y + a.z * b.z + a.w * b.w;
}

__device__ __forceinline__ unsigned short f2bf(float x) {   // RNE
  union { float f; unsigned u; } v; v.f = x;
  unsigned r = v.u + 0x7fffu + ((v.u >> 16) & 1u);
  return (unsigned short)(r >> 16);
}

__device__ __forceinline__ short8 pack8(float4 u, float4 v) {
  short8 s;
  s[0] = (short)f2bf(u.x); s[1] = (short)f2bf(u.y); s[2] = (short)f2bf(u.z); s[3] = (short)f2bf(u.w);
  s[4] = (short)f2bf(v.x); s[5] = (short)f2bf(v.y); s[6] = (short)f2bf(v.z); s[7] = (short)f2bf(v.w);
  return s;
}

// ---------------------------------------------------------------------------
// Prepass, grid 704:
//  blocks 0..127   : stage image (rows 36..47 zero) -> A fragments + G via MFMA
//  blocks 128..639 : caption fp32->bf16 cvt into fragment-major layout
//  blocks 640..703 : caption sq-norms (fp32)
// A-frag chunk index: ((t*2+ks)*3+x)*64 + lane; lane(lr,lk) holds
// row=x*16+lr, k=t*64+ks*32+lk*8..+8. Pad rows are exact zeros.
// ---------------------------------------------------------------------------
extern "C" __global__ __launch_bounds__(256, 2)
void scan_pre(const float* __restrict__ images, const float* __restrict__ captions,
              float* __restrict__ ws)
{
  __shared__ unsigned short sI[48 * 520];
  const int tid = threadIdx.x;
  const int bx = blockIdx.x;
  const short8 z8 = {0, 0, 0, 0, 0, 0, 0, 0};

  if (bx < 128) {
    const int i = bx;
    const float* gi = images + (size_t)i * Rn * Dn;
    for (int q = 0; q < 9; ++q) {
      int ch = tid + q * 256;
      int r = ch >> 6, c8 = (ch & 63) * 8;
      float4 u = *reinterpret_cast<const float4*>(gi + r * Dn + c8);
      float4 v = *reinterpret_cast<const float4*>(gi + r * Dn + c8 + 4);
      *reinterpret_cast<short8*>(&sI[r * 520 + c8]) = pack8(u, v);
    }
    for (int q = 0; q < 3; ++q) {
      int ch = tid + q * 256;
      int r = 36 + (ch >> 6), c8 = (ch & 63) * 8;
      *reinterpret_cast<short8*>(&sI[r * 520 + c8]) = z8;
    }
    __syncthreads();

    // A fragments (3072 chunks of 8 shorts; 12/thread), coalesced writes
    unsigned short* af = (unsigned short*)(ws + AFOFF) + (size_t)i * 24576;
    #pragma unroll
    for (int q = 0; q < 12; ++q) {
      int c = tid + q * 256;            // 0..3071
      int ln = c & 63, g = c >> 6;      // g 0..47
      int x = g % 3, ksq = g / 3;       // ksq = t*2+ks
      int ks = ksq & 1, t = ksq >> 1;
      int lr = ln & 15, lk = ln >> 4;
      short8 v = *reinterpret_cast<const short8*>(
          &sI[(x * 16 + lr) * 520 + t * 64 + ks * 32 + lk * 8]);
      *reinterpret_cast<short8*>(af + (size_t)c * 8) = v;
    }

    // G via MFMA (unchanged)
    const int lane = tid & 63, wv = tid >> 6;
    const int lr = lane & 15, lk = lane >> 4;
    unsigned short* gb = (unsigned short*)(ws + GBOFF) + (size_t)i * 48 * 64;
    for (int t = wv; t < 9; t += 4) {
      const int mt = t / 3, nt = t - mt * 3;
      f32x4 acc = {0.f, 0.f, 0.f, 0.f};
      for (int k = 0; k < 16; ++k) {
        short8 af2 = *reinterpret_cast<const short8*>(&sI[(mt * 16 + lr) * 520 + k * 32 + lk * 8]);
        short8 bf2 = *reinterpret_cast<const short8*>(&sI[(nt * 16 + lr) * 520 + k * 32 + lk * 8]);
        acc = __builtin_amdgcn_mfma_f32_16x16x32_bf16(af2, bf2, acc, 0, 0, 0);
      }
      #pragma unroll
      for (int j = 0; j < 4; ++j)
        gb[(mt * 16 + lk * 4 + j) * 64 + nt * 16 + lr] = f2bf(acc[j]);
    }
    if (tid < 96) {
      int r = tid >> 1, h = tid & 1;
      *reinterpret_cast<short8*>(gb + r * 64 + 48 + h * 8) = z8;
    }
    return;
  }
  if (bx < 640) {
    const int chunk = (bx - 128) * 256 + tid;        // 0..131071 short8 chunks
    const int c  = chunk >> 11;
    const int cc = chunk & 2047;
    const int ln = cc & 63;
    const int fc = cc >> 6;             // (t,ks,y)
    const int t  = fc >> 2;
    const int ks = (fc >> 1) & 1;
    const int y  = fc & 1;
    const int lr = ln & 15, lk = ln >> 4;
    const float* src = captions + ((size_t)c * Ln + y * 16 + lr) * Dn
                     + t * 64 + ks * 32 + lk * 8;
    float4 u = *reinterpret_cast<const float4*>(src);
    float4 v = *reinterpret_cast<const float4*>(src + 4);
    unsigned short* dst = (unsigned short*)(ws + BBOFF) + (size_t)chunk * 8;
    *reinterpret_cast<short8*>(dst) = pack8(u, v);
    return;
  }
  {
    const int c = bx - 640;
    const float* gc = captions + (size_t)c * Ln * Dn;
    const int l = tid >> 3, p = tid & 7;
    float s = 0.f;
    #pragma unroll
    for (int t = 0; t < 16; ++t) {
      float4 v = *reinterpret_cast<const float4*>(gc + l * Dn + p * 64 + t * 4);
      s += dot4(v, v);
    }
    s += __shfl_xor(s, 1, 64); s += __shfl_xor(s, 2, 64); s += __shfl_xor(s, 4, 64);
    if (p == 0) ws[CNOFF + c * Ln + l] = s;
  }
}

// ---------------------------------------------------------------------------
// Fused: block = 1 image x 4 captions (256 thr, wave = caption). BOTH A and B
// fragments direct from pre-shuffled global (coalesced, L2/L3-hot), 1-step
// prefetch. NO staging, NO barriers. ET in a small per-wave-private LDS
// buffer (tails zeroed). Epilogue arithmetic identical to r12. Grid 2048.
// ---------------------------------------------------------------------------
extern "C" __global__ __launch_bounds__(256, 3)
void scan_fused(const float* __restrict__ ws, const int* __restrict__ cap_lens,
                float* __restrict__ out)
{
  __shared__ unsigned short ETb[4][1568];      // 12.5 KB, per-wave private
  const unsigned short* AF = (const unsigned short*)(ws + AFOFF);
  const unsigned short* Bf = (const unsigned short*)(ws + BBOFF);
  const unsigned short* GbAll = (const unsigned short*)(ws + GBOFF);
  const float* cnArr = ws + CNOFF;

  const int tid = threadIdx.x;
  int bid = blockIdx.x;                        // 2048 blocks; 8 XCD chunks of 256
  bid = (bid & 7) * 256 + (bid >> 3);
  const int ig = bid >> 4;
  const int cg = bid & 15;
  const int lane = tid & 63, wv = tid >> 6;
  const int lr = lane & 15, lk = lane >> 4;
  const int cap = cg * 4 + wv;
  const int len = cap_lens[cap];
  const short8 z8 = {0, 0, 0, 0, 0, 0, 0, 0};

  // zero this wave's ET tail (reads touch [1536,1552); write once, in-wave)
  if (lane < 4)
    *reinterpret_cast<short8*>(&ETb[wv][1536 + lane * 8]) = z8;

  // fragment pointers
  const unsigned short* gAf = AF + (size_t)ig * 24576 + lane * 8;
  const unsigned short* gBp = Bf + (size_t)cap * 16384 + lane * 8;

  f32x4 acc[3][2];
  #pragma unroll
  for (int x = 0; x < 3; ++x)
    #pragma unroll
    for (int y = 0; y < 2; ++y) acc[x][y] = {0.f, 0.f, 0.f, 0.f};

  // 1-step-deep prefetch of all 10 fragments (6 A + 4 B)
  short8 ac[6], an[6], bc[4], bn[4];
  #pragma unroll
  for (int f = 0; f < 6; ++f)
    ac[f] = *reinterpret_cast<const short8*>(gAf + f * 512);       // f = ks*3+x
  #pragma unroll
  for (int f = 0; f < 4; ++f)
    bc[f] = *reinterpret_cast<const short8*>(gBp + f * 512);       // f = ks*2+y

  #pragma unroll 2
  for (int t = 0; t < 8; ++t) {
    if (t < 7) {
      #pragma unroll
      for (int f = 0; f < 6; ++f)
        an[f] = *reinterpret_cast<const short8*>(gAf + ((t + 1) * 6 + f) * 512);
      #pragma unroll
      for (int f = 0; f < 4; ++f)
        bn[f] = *reinterpret_cast<const short8*>(gBp + ((t + 1) * 4 + f) * 512);
    }
    #pragma unroll
    for (int ks = 0; ks < 2; ++ks)
      #pragma unroll
      for (int x = 0; x < 3; ++x)
        #pragma unroll
        for (int y = 0; y < 2; ++y)
          acc[x][y] = __builtin_amdgcn_mfma_f32_16x16x32_bf16(
              ac[ks * 3 + x], bc[ks * 2 + y], acc[x][y], 0, 0, 0);
    if (t < 7) {
      #pragma unroll
      for (int f = 0; f < 6; ++f) ac[f] = an[f];
      #pragma unroll
      for (int f = 0; f < 4; ++f) bc[f] = bn[f];
    }
  }

  // prefetch G fragments + caption norms while VALU epilogue runs
  const unsigned short* Gb = GbAll + (size_t)ig * 48 * 64;
  short8 gfr[3][2];
  #pragma unroll
  for (int x = 0; x < 3; ++x)
    #pragma unroll
    for (int ks = 0; ks < 2; ++ks)
      gfr[x][ks] = *reinterpret_cast<const short8*>(Gb + (x * 16 + lr) * 64 + ks * 32 + lk * 8);
  const float cn0 = cnArr[cap * 32 + lr];
  const float cn1 = cnArr[cap * 32 + 16 + lr];

  // ---- epilogue (per wave = per caption; identical arithmetic to r12) ----
  float s[3][2][4];
  #pragma unroll
  for (int x = 0; x < 3; ++x)
    #pragma unroll
    for (int y = 0; y < 2; ++y) {
      const int l = y * 16 + lr;
      #pragma unroll
      for (int j = 0; j < 4; ++j) {
        float v = acc[x][y][j];
        v = v > 0.f ? v : SLOPE * v;
        if (l >= len) v = 0.f;
        s[x][y][j] = v;
      }
    }

  float zinv[3][4];
  #pragma unroll
  for (int x = 0; x < 3; ++x)
    #pragma unroll
    for (int j = 0; j < 4; ++j) {
      float t = s[x][0][j] * s[x][0][j] + s[x][1][j] * s[x][1][j];
      t += __shfl_xor(t, 1, 64); t += __shfl_xor(t, 2, 64);
      t += __shfl_xor(t, 4, 64); t += __shfl_xor(t, 8, 64);
      zinv[x][j] = LSM / (sqrtf(t) + EPSf);
    }

  const bool x2ok = (lk == 0);
  float mcol[2] = {-1e30f, -1e30f};
  #pragma unroll
  for (int x = 0; x < 3; ++x)
    #pragma unroll
    for (int y = 0; y < 2; ++y)
      #pragma unroll
      for (int j = 0; j < 4; ++j) {
        float zz = s[x][y][j] * zinv[x][j];
        s[x][y][j] = zz;
        if (x < 2 || x2ok) mcol[y] = fmaxf(mcol[y], zz);
      }
  #pragma unroll
  for (int y = 0; y < 2; ++y) {
    mcol[y] = fmaxf(mcol[y], __shfl_xor(mcol[y], 16, 64));
    mcol[y] = fmaxf(mcol[y], __shfl_xor(mcol[y], 32, 64));
  }

  float e[3][2][4];
  float esum[2] = {0.f, 0.f}, num[2] = {0.f, 0.f};
  #pragma unroll
  for (int x = 0; x < 3; ++x)
    #pragma unroll
    for (int y = 0; y < 2; ++y)
      #pragma unroll
      for (int j = 0; j < 4; ++j) {
        float ev = (x < 2 || x2ok) ? __expf(s[x][y][j] - mcol[y]) : 0.f;
        e[x][y][j] = ev;
        esum[y] += ev;
        num[y] = fmaf(ev, acc[x][y][j], num[y]);
      }
  #pragma unroll
  for (int y = 0; y < 2; ++y) {
    esum[y] += __shfl_xor(esum[y], 16, 64); esum[y] += __shfl_xor(esum[y], 32, 64);
    num[y]  += __shfl_xor(num[y], 16, 64);  num[y]  += __shfl_xor(num[y], 32, 64);
  }

  // ---- ET (bf16, transposed) into this wave's private buffer; no barrier ---
  unsigned short* ET = ETb[wv];
  #pragma unroll
  for (int x = 0; x < 3; ++x)
    #pragma unroll
    for (int y = 0; y < 2; ++y)
      #pragma unroll
      for (int j = 0; j < 4; ++j)
        ET[(y * 16 + lr) * 48 + (x * 16 + lk * 4 + j)] = f2bf(e[x][y][j]);

  f32x4 vac[3][2];
  #pragma unroll
  for (int x = 0; x < 3; ++x)
    #pragma unroll
    for (int y = 0; y < 2; ++y) vac[x][y] = {0.f, 0.f, 0.f, 0.f};
  #pragma unroll
  for (int ks = 0; ks < 2; ++ks) {
    short8 efr[2];
    #pragma unroll
    for (int y = 0; y < 2; ++y)
      efr[y] = *reinterpret_cast<const short8*>(&ET[(y * 16 + lr) * 48 + ks * 32 + lk * 8]);
    #pragma unroll
    for (int x = 0; x < 3; ++x)
      #pragma unroll
      for (int y = 0; y < 2; ++y)
        vac[x][y] = __builtin_amdgcn_mfma_f32_16x16x32_bf16(gfr[x][ks], efr[y], vac[x][y], 0, 0, 0);
  }
  float wn[2] = {0.f, 0.f};
  #pragma unroll
  for (int x = 0; x < 3; ++x)
    #pragma unroll
    for (int y = 0; y < 2; ++y)
      #pragma unroll
      for (int j = 0; j < 4; ++j)
        wn[y] = fmaf(e[x][y][j], vac[x][y][j], wn[y]);
  #pragma unroll
  for (int y = 0; y < 2; ++y) {
    wn[y] += __shfl_xor(wn[y], 16, 64); wn[y] += __shfl_xor(wn[y], 32, 64);
  }

  float sc[2];
  #pragma unroll
  for (int y = 0; y < 2; ++y) {
    const int l = y * 16 + lr;
    const float cn = y ? cn1 : cn0;
    float inv = 1.f / esum[y];
    float nm = num[y] * inv;
    float w = fmaxf(wn[y], 0.f) * inv * inv;
    float den = fmaxf(sqrtf(cn), EPSf) * fmaxf(sqrtf(w), EPSf);
    sc[y] = (l < len) ? (nm / den) * LLSE : -INFINITY;
  }
  float mx = fmaxf(sc[0], sc[1]);
  mx = fmaxf(mx, __shfl_xor(mx, 1, 64)); mx = fmaxf(mx, __shfl_xor(mx, 2, 64));
  mx = fmaxf(mx, __shfl_xor(mx, 4, 64)); mx = fmaxf(mx, __shfl_xor(mx, 8, 64));
  float ex = __expf(sc[0] - mx) + __expf(sc[1] - mx);
  ex += __shfl_xor(ex, 1, 64); ex += __shfl_xor(ex, 2, 64);
  ex += __shfl_xor(ex, 4, 64); ex += __shfl_xor(ex, 8, 64);
  if (lane == 0) out[ig * Cn + cap] = (mx + __logf(ex)) / LLSE;
}

extern "C" void kernel_launch(void* const* d_in, const int* in_sizes, int n_in,
                              void* d_out, int out_size, void* d_ws, size_t ws_size,
                              hipStream_t stream) {
  const float* images   = (const float*)d_in[0];
  const float* captions = (const float*)d_in[1];
  const int*   cap_lens = (const int*)d_in[2];
  float* out = (float*)d_out;
  float* ws  = (float*)d_ws;
  if (ws_size < WSFLOATS * sizeof(float)) return;

  hipLaunchKernelGGL(scan_pre, dim3(704), dim3(256), 0, stream,
                     images, captions, ws);
  hipLaunchKernelGGL(scan_fused, dim3(In * 16), dim3(256), 0, stream,
                     ws, cap_lens, out);
}

// Round 16
// 41.095 us; speedup vs baseline: 1.0726x; 1.0298x over previous
//
#include <hip/hip_runtime.h>
#include <math.h>

constexpr int In = 128, Rn = 36, Cn = 64, Ln = 32, Dn = 512;
constexpr int Mn = In * Rn;              // 4608
constexpr int Nn = Cn * Ln;              // 2048
// ws layout (float units)
constexpr size_t AFOFF = 0;                               // images bf16 FRAGMENT-MAJOR
constexpr size_t AFSZ  = (size_t)In * 24576 / 2;          // 8t*2ks*3x*64lane*8 shorts/img
constexpr size_t BBOFF = AFSZ;                            // captions bf16 FRAGMENT-MAJOR
constexpr size_t GBOFF = BBOFF + (size_t)Nn * Dn / 2;     // Gb bf16 [In][48][64]
constexpr size_t CNOFF = GBOFF + (size_t)In * 48 * 64 / 2;
constexpr size_t WSFLOATS = CNOFF + (size_t)Cn * Ln;      // ~9.2 MB
constexpr float EPSf = 1e-8f, LLSE = 6.0f, LSM = 9.0f, SLOPE = 0.1f;

using short8 = __attribute__((ext_vector_type(8))) short;
using f32x4  = __attribute__((ext_vector_type(4))) float;

__device__ __forceinline__ float dot4(float4 a, float4 b) {
  return a.x * b.x + a.y * b.y + a.z * b.z + a.w * b.w;
}

__device__ __forceinline__ unsigned short f2bf(float x) {   // RNE
  union { float f; unsigned u; } v; v.f = x;
  unsigned r = v.u + 0x7fffu + ((v.u >> 16) & 1u);
  return (unsigned short)(r >> 16);
}

__device__ __forceinline__ short8 pack8(float4 u, float4 v) {
  short8 s;
  s[0] = (short)f2bf(u.x); s[1] = (short)f2bf(u.y); s[2] = (short)f2bf(u.z); s[3] = (short)f2bf(u.w);
  s[4] = (short)f2bf(v.x); s[5] = (short)f2bf(v.y); s[6] = (short)f2bf(v.z); s[7] = (short)f2bf(v.w);
  return s;
}

// 16-lane-row reductions on the VALU via DPP row_ror (no LDS pipe).
// CTRL: 0x121=ror1, 0x122=ror2, 0x124=ror4, 0x128=ror8.
template<int CTRL>
__device__ __forceinline__ float dppadd(float v) {
  union { float f; int i; } s, r;
  s.f = v;
  r.i = __builtin_amdgcn_update_dpp(s.i, s.i, CTRL, 0xF, 0xF, false);
  return v + r.f;
}
template<int CTRL>
__device__ __forceinline__ float dppmax(float v) {
  union { float f; int i; } s, r;
  s.f = v;
  r.i = __builtin_amdgcn_update_dpp(s.i, s.i, CTRL, 0xF, 0xF, false);
  return fmaxf(v, r.f);
}
__device__ __forceinline__ float dppsum16(float v) {
  v = dppadd<0x128>(v); v = dppadd<0x124>(v);
  v = dppadd<0x122>(v); v = dppadd<0x121>(v);
  return v;
}
__device__ __forceinline__ float dppmax16(float v) {
  v = dppmax<0x128>(v); v = dppmax<0x124>(v);
  v = dppmax<0x122>(v); v = dppmax<0x121>(v);
  return v;
}

// ---------------------------------------------------------------------------
// Prepass, grid 704 (unchanged from round 15):
//  blocks 0..127   : stage image (rows 36..47 zero) -> A fragments + G via MFMA
//  blocks 128..639 : caption fp32->bf16 cvt into fragment-major layout
//  blocks 640..703 : caption sq-norms (fp32)
// ---------------------------------------------------------------------------
extern "C" __global__ __launch_bounds__(256, 2)
void scan_pre(const float* __restrict__ images, const float* __restrict__ captions,
              float* __restrict__ ws)
{
  __shared__ unsigned short sI[48 * 520];
  const int tid = threadIdx.x;
  const int bx = blockIdx.x;
  const short8 z8 = {0, 0, 0, 0, 0, 0, 0, 0};

  if (bx < 128) {
    const int i = bx;
    const float* gi = images + (size_t)i * Rn * Dn;
    for (int q = 0; q < 9; ++q) {
      int ch = tid + q * 256;
      int r = ch >> 6, c8 = (ch & 63) * 8;
      float4 u = *reinterpret_cast<const float4*>(gi + r * Dn + c8);
      float4 v = *reinterpret_cast<const float4*>(gi + r * Dn + c8 + 4);
      *reinterpret_cast<short8*>(&sI[r * 520 + c8]) = pack8(u, v);
    }
    for (int q = 0; q < 3; ++q) {
      int ch = tid + q * 256;
      int r = 36 + (ch >> 6), c8 = (ch & 63) * 8;
      *reinterpret_cast<short8*>(&sI[r * 520 + c8]) = z8;
    }
    __syncthreads();

    unsigned short* af = (unsigned short*)(ws + AFOFF) + (size_t)i * 24576;
    #pragma unroll
    for (int q = 0; q < 12; ++q) {
      int c = tid + q * 256;            // 0..3071
      int ln = c & 63, g = c >> 6;      // g 0..47
      int x = g % 3, ksq = g / 3;       // ksq = t*2+ks
      int ks = ksq & 1, t = ksq >> 1;
      int lr = ln & 15, lk = ln >> 4;
      short8 v = *reinterpret_cast<const short8*>(
          &sI[(x * 16 + lr) * 520 + t * 64 + ks * 32 + lk * 8]);
      *reinterpret_cast<short8*>(af + (size_t)c * 8) = v;
    }

    const int lane = tid & 63, wv = tid >> 6;
    const int lr = lane & 15, lk = lane >> 4;
    unsigned short* gb = (unsigned short*)(ws + GBOFF) + (size_t)i * 48 * 64;
    for (int t = wv; t < 9; t += 4) {
      const int mt = t / 3, nt = t - mt * 3;
      f32x4 acc = {0.f, 0.f, 0.f, 0.f};
      for (int k = 0; k < 16; ++k) {
        short8 af2 = *reinterpret_cast<const short8*>(&sI[(mt * 16 + lr) * 520 + k * 32 + lk * 8]);
        short8 bf2 = *reinterpret_cast<const short8*>(&sI[(nt * 16 + lr) * 520 + k * 32 + lk * 8]);
        acc = __builtin_amdgcn_mfma_f32_16x16x32_bf16(af2, bf2, acc, 0, 0, 0);
      }
      #pragma unroll
      for (int j = 0; j < 4; ++j)
        gb[(mt * 16 + lk * 4 + j) * 64 + nt * 16 + lr] = f2bf(acc[j]);
    }
    if (tid < 96) {
      int r = tid >> 1, h = tid & 1;
      *reinterpret_cast<short8*>(gb + r * 64 + 48 + h * 8) = z8;
    }
    return;
  }
  if (bx < 640) {
    const int chunk = (bx - 128) * 256 + tid;        // 0..131071 short8 chunks
    const int c  = chunk >> 11;
    const int cc = chunk & 2047;
    const int ln = cc & 63;
    const int fc = cc >> 6;             // (t,ks,y)
    const int t  = fc >> 2;
    const int ks = (fc >> 1) & 1;
    const int y  = fc & 1;
    const int lr = ln & 15, lk = ln >> 4;
    const float* src = captions + ((size_t)c * Ln + y * 16 + lr) * Dn
                     + t * 64 + ks * 32 + lk * 8;
    float4 u = *reinterpret_cast<const float4*>(src);
    float4 v = *reinterpret_cast<const float4*>(src + 4);
    unsigned short* dst = (unsigned short*)(ws + BBOFF) + (size_t)chunk * 8;
    *reinterpret_cast<short8*>(dst) = pack8(u, v);
    return;
  }
  {
    const int c = bx - 640;
    const float* gc = captions + (size_t)c * Ln * Dn;
    const int l = tid >> 3, p = tid & 7;
    float s = 0.f;
    #pragma unroll
    for (int t = 0; t < 16; ++t) {
      float4 v = *reinterpret_cast<const float4*>(gc + l * Dn + p * 64 + t * 4);
      s += dot4(v, v);
    }
    s += __shfl_xor(s, 1, 64); s += __shfl_xor(s, 2, 64); s += __shfl_xor(s, 4, 64);
    if (p == 0) ws[CNOFF + c * Ln + l] = s;
  }
}

// ---------------------------------------------------------------------------
// Fused (r15 structure, proven 42.3us): block = 1 image x 4 captions.
// A+B fragments direct from pre-shuffled global; no staging, no barriers.
// THIS ROUND: 16-lane reductions (zinv, LSE) moved from ds_bpermute to DPP.
// ---------------------------------------------------------------------------
extern "C" __global__ __launch_bounds__(256, 3)
void scan_fused(const float* __restrict__ ws, const int* __restrict__ cap_lens,
                float* __restrict__ out)
{
  __shared__ unsigned short ETb[4][1568];      // 12.5 KB, per-wave private
  const unsigned short* AF = (const unsigned short*)(ws + AFOFF);
  const unsigned short* Bf = (const unsigned short*)(ws + BBOFF);
  const unsigned short* GbAll = (const unsigned short*)(ws + GBOFF);
  const float* cnArr = ws + CNOFF;

  const int tid = threadIdx.x;
  int bid = blockIdx.x;                        // 2048 blocks; 8 XCD chunks of 256
  bid = (bid & 7) * 256 + (bid >> 3);
  const int ig = bid >> 4;
  const int cg = bid & 15;
  const int lane = tid & 63, wv = tid >> 6;
  const int lr = lane & 15, lk = lane >> 4;
  const int cap = cg * 4 + wv;
  const int len = cap_lens[cap];
  const short8 z8 = {0, 0, 0, 0, 0, 0, 0, 0};

  if (lane < 4)
    *reinterpret_cast<short8*>(&ETb[wv][1536 + lane * 8]) = z8;

  const unsigned short* gAf = AF + (size_t)ig * 24576 + lane * 8;
  const unsigned short* gBp = Bf + (size_t)cap * 16384 + lane * 8;

  f32x4 acc[3][2];
  #pragma unroll
  for (int x = 0; x < 3; ++x)
    #pragma unroll
    for (int y = 0; y < 2; ++y) acc[x][y] = {0.f, 0.f, 0.f, 0.f};

  short8 ac[6], an[6], bc[4], bn[4];
  #pragma unroll
  for (int f = 0; f < 6; ++f)
    ac[f] = *reinterpret_cast<const short8*>(gAf + f * 512);       // f = ks*3+x
  #pragma unroll
  for (int f = 0; f < 4; ++f)
    bc[f] = *reinterpret_cast<const short8*>(gBp + f * 512);       // f = ks*2+y

  #pragma unroll 2
  for (int t = 0; t < 8; ++t) {
    if (t < 7) {
      #pragma unroll
      for (int f = 0; f < 6; ++f)
        an[f] = *reinterpret_cast<const short8*>(gAf + ((t + 1) * 6 + f) * 512);
      #pragma unroll
      for (int f = 0; f < 4; ++f)
        bn[f] = *reinterpret_cast<const short8*>(gBp + ((t + 1) * 4 + f) * 512);
    }
    #pragma unroll
    for (int ks = 0; ks < 2; ++ks)
      #pragma unroll
      for (int x = 0; x < 3; ++x)
        #pragma unroll
        for (int y = 0; y < 2; ++y)
          acc[x][y] = __builtin_amdgcn_mfma_f32_16x16x32_bf16(
              ac[ks * 3 + x], bc[ks * 2 + y], acc[x][y], 0, 0, 0);
    if (t < 7) {
      #pragma unroll
      for (int f = 0; f < 6; ++f) ac[f] = an[f];
      #pragma unroll
      for (int f = 0; f < 4; ++f) bc[f] = bn[f];
    }
  }

  const unsigned short* Gb = GbAll + (size_t)ig * 48 * 64;
  short8 gfr[3][2];
  #pragma unroll
  for (int x = 0; x < 3; ++x)
    #pragma unroll
    for (int ks = 0; ks < 2; ++ks)
      gfr[x][ks] = *reinterpret_cast<const short8*>(Gb + (x * 16 + lr) * 64 + ks * 32 + lk * 8);
  const float cn0 = cnArr[cap * 32 + lr];
  const float cn1 = cnArr[cap * 32 + 16 + lr];

  // ---- epilogue (per wave = per caption) ----
  float s[3][2][4];
  #pragma unroll
  for (int x = 0; x < 3; ++x)
    #pragma unroll
    for (int y = 0; y < 2; ++y) {
      const int l = y * 16 + lr;
      #pragma unroll
      for (int j = 0; j < 4; ++j) {
        float v = acc[x][y][j];
        v = v > 0.f ? v : SLOPE * v;
        if (l >= len) v = 0.f;
        s[x][y][j] = v;
      }
    }

  // row l2-norms: sum over 32 cols = 2 in-lane + 16-lane DPP row reduce
  float zinv[3][4];
  #pragma unroll
  for (int x = 0; x < 3; ++x)
    #pragma unroll
    for (int j = 0; j < 4; ++j) {
      float t = s[x][0][j] * s[x][0][j] + s[x][1][j] * s[x][1][j];
      t = dppsum16(t);
      zinv[x][j] = LSM / (sqrtf(t) + EPSf);
    }

  const bool x2ok = (lk == 0);
  float mcol[2] = {-1e30f, -1e30f};
  #pragma unroll
  for (int x = 0; x < 3; ++x)
    #pragma unroll
    for (int y = 0; y < 2; ++y)
      #pragma unroll
      for (int j = 0; j < 4; ++j) {
        float zz = s[x][y][j] * zinv[x][j];
        s[x][y][j] = zz;
        if (x < 2 || x2ok) mcol[y] = fmaxf(mcol[y], zz);
      }
  #pragma unroll
  for (int y = 0; y < 2; ++y) {
    mcol[y] = fmaxf(mcol[y], __shfl_xor(mcol[y], 16, 64));
    mcol[y] = fmaxf(mcol[y], __shfl_xor(mcol[y], 32, 64));
  }

  float e[3][2][4];
  float esum[2] = {0.f, 0.f}, num[2] = {0.f, 0.f};
  #pragma unroll
  for (int x = 0; x < 3; ++x)
    #pragma unroll
    for (int y = 0; y < 2; ++y)
      #pragma unroll
      for (int j = 0; j < 4; ++j) {
        float ev = (x < 2 || x2ok) ? __expf(s[x][y][j] - mcol[y]) : 0.f;
        e[x][y][j] = ev;
        esum[y] += ev;
        num[y] = fmaf(ev, acc[x][y][j], num[y]);
      }
  #pragma unroll
  for (int y = 0; y < 2; ++y) {
    esum[y] += __shfl_xor(esum[y], 16, 64); esum[y] += __shfl_xor(esum[y], 32, 64);
    num[y]  += __shfl_xor(num[y], 16, 64);  num[y]  += __shfl_xor(num[y], 32, 64);
  }

  // ---- ET (bf16, transposed) into this wave's private buffer; no barrier ---
  unsigned short* ET = ETb[wv];
  #pragma unroll
  for (int x = 0; x < 3; ++x)
    #pragma unroll
    for (int y = 0; y < 2; ++y)
      #pragma unroll
      for (int j = 0; j < 4; ++j)
        ET[(y * 16 + lr) * 48 + (x * 16 + lk * 4 + j)] = f2bf(e[x][y][j]);

  f32x4 vac[3][2];
  #pragma unroll
  for (int x = 0; x < 3; ++x)
    #pragma unroll
    for (int y = 0; y < 2; ++y) vac[x][y] = {0.f, 0.f, 0.f, 0.f};
  #pragma unroll
  for (int ks = 0; ks < 2; ++ks) {
    short8 efr[2];
    #pragma unroll
    for (int y = 0; y < 2; ++y)
      efr[y] = *reinterpret_cast<const short8*>(&ET[(y * 16 + lr) * 48 + ks * 32 + lk * 8]);
    #pragma unroll
    for (int x = 0; x < 3; ++x)
      #pragma unroll
      for (int y = 0; y < 2; ++y)
        vac[x][y] = __builtin_amdgcn_mfma_f32_16x16x32_bf16(gfr[x][ks], efr[y], vac[x][y], 0, 0, 0);
  }
  float wn[2] = {0.f, 0.f};
  #pragma unroll
  for (int x = 0; x < 3; ++x)
    #pragma unroll
    for (int y = 0; y < 2; ++y)
      #pragma unroll
      for (int j = 0; j < 4; ++j)
        wn[y] = fmaf(e[x][y][j], vac[x][y][j], wn[y]);
  #pragma unroll
  for (int y = 0; y < 2; ++y) {
    wn[y] += __shfl_xor(wn[y], 16, 64); wn[y] += __shfl_xor(wn[y], 32, 64);
  }

  float sc[2];
  #pragma unroll
  for (int y = 0; y < 2; ++y) {
    const int l = y * 16 + lr;
    const float cn = y ? cn1 : cn0;
    float inv = 1.f / esum[y];
    float nm = num[y] * inv;
    float w = fmaxf(wn[y], 0.f) * inv * inv;
    float den = fmaxf(sqrtf(cn), EPSf) * fmaxf(sqrtf(w), EPSf);
    sc[y] = (l < len) ? (nm / den) * LLSE : -INFINITY;
  }
  // masked LSE over the caption's 32 cols: 2 in-lane + 16-lane DPP reduce
  float mx = fmaxf(sc[0], sc[1]);
  mx = dppmax16(mx);
  float ex = __expf(sc[0] - mx) + __expf(sc[1] - mx);
  ex = dppsum16(ex);
  if (lane == 0) out[ig * Cn + cap] = (mx + __logf(ex)) / LLSE;
}

extern "C" void kernel_launch(void* const* d_in, const int* in_sizes, int n_in,
                              void* d_out, int out_size, void* d_ws, size_t ws_size,
                              hipStream_t stream) {
  const float* images   = (const float*)d_in[0];
  const float* captions = (const float*)d_in[1];
  const int*   cap_lens = (const int*)d_in[2];
  float* out = (float*)d_out;
  float* ws  = (float*)d_ws;
  if (ws_size < WSFLOATS * sizeof(float)) return;

  hipLaunchKernelGGL(scan_pre, dim3(704), dim3(256), 0, stream,
                     images, captions, ws);
  hipLaunchKernelGGL(scan_fused, dim3(In * 16), dim3(256), 0, stream,
                     ws, cap_lens, out);
}